// Round 3
// baseline (6669.897 us; speedup 1.0000x reference)
//
#include <hip/hip_runtime.h>
#include <hip/hip_bf16.h>

#define BB 32
#define NN 128
#define TT 16
#define FN 16
#define FE 8
#define FG 8
#define FH 16
#define HH 128
#define DEC 64

// ws layout (floats):
// base_node [524288]  @ 0
// We        [1024]    @ 524288
// mg        [4096]    @ 525312
// m1p       [524288]  @ 529408
// m2        [524288]  @ 1053696
// o1        [524288]  @ 1577984
// hidden    [524288]  @ 2102272
// eg        [4194304] @ 2626560
// jl (int)  [524288]  @ 6820864
// cnt (int) [4096]    @ 7345152
// wm1t      [32768]   @ 7349248
// wm2t      [32768]   @ 7382016
// wo1t      [32768]   @ 7414784
// wo2t      [16384]   @ 7447552
// wdnt      [8192]    @ 7463936
// wdet      [8192]    @ 7472128
// end 7480320 floats = 29.9 MB

__global__ __launch_bounds__(HH) void prep1(const float* __restrict__ node,
                                            const float* __restrict__ Wn,
                                            float* __restrict__ base_node,
                                            float* __restrict__ hidden) {
    int row = blockIdx.x;
    int h = threadIdx.x;
    float acc = 0.f;
#pragma unroll
    for (int f = 0; f < FN; ++f)
        acc += node[row * FN + f] * Wn[f * HH + h];
    base_node[row * HH + h] = acc;
    hidden[row * HH + h] = 0.f;
}

__global__ __launch_bounds__(HH) void prep2(const float* __restrict__ graph,
                                            const float* __restrict__ Wg,
                                            const float* __restrict__ Wmg,
                                            const float* __restrict__ Wee,
                                            const float* __restrict__ Wme,
                                            float* __restrict__ mg,
                                            float* __restrict__ We) {
    int h = threadIdx.x;
    if (blockIdx.x < BB) {
        int b = blockIdx.x;
        __shared__ float gf[HH];
        float acc = 0.f;
#pragma unroll
        for (int f = 0; f < FG; ++f) acc += graph[b * FG + f] * Wg[f * HH + h];
        gf[h] = acc;
        __syncthreads();
        float a2 = 0.f;
#pragma unroll 4
        for (int k = 0; k < HH; ++k) a2 += gf[k] * Wmg[k * HH + h];
        mg[b * HH + h] = a2;
    } else {
#pragma unroll
        for (int f = 0; f < FE; ++f) {
            float acc = 0.f;
#pragma unroll 4
            for (int k = 0; k < HH; ++k) acc += Wee[f * HH + k] * Wme[k * HH + h];
            We[f * HH + h] = acc;
        }
    }
}

// Compact valid senders; pad to multiple of 32 with duplicates of entry 0
// (max is idempotent, so dups are harmless and give fixed trip counts).
__global__ __launch_bounds__(HH) void prep3(const float* __restrict__ edge,
                                            const int* __restrict__ adj,
                                            float* __restrict__ eg,
                                            int* __restrict__ jl,
                                            int* __restrict__ cnt) {
    int bi = blockIdx.x;
    int j = threadIdx.x;
    __shared__ int w0cnt, totc, j0;
    bool valid = adj[(size_t)bi * NN + j] > 0;
    unsigned long long mask = __ballot(valid);
    int lane = j & 63;
    int wave = j >> 6;
    int prefix = __popcll(mask & ((1ull << lane) - 1ull));
    int wcount = __popcll(mask);
    if (wave == 0 && lane == 0) w0cnt = wcount;
    __syncthreads();
    int base = (wave == 1) ? w0cnt : 0;
    if (wave == 1 && lane == 0) totc = w0cnt + wcount;
    int pos = base + prefix;
    if (valid && pos == 0) j0 = j;
    __syncthreads();
    int c = totc;
    int cpad = (c + 31) & ~31;
    if (j == 0) cnt[bi] = cpad;
    if (valid) {
        jl[bi * NN + pos] = j;
        const float4* src = (const float4*)(edge + ((size_t)bi * NN + j) * FE);
        float4* dst = (float4*)(eg + ((size_t)bi * NN + pos) * FE);
        dst[0] = src[0];
        dst[1] = src[1];
    }
    if (j >= c && j < cpad) {
        jl[bi * NN + j] = j0;
        const float4* src = (const float4*)(edge + ((size_t)bi * NN + j0) * FE);
        float4* dst = (float4*)(eg + ((size_t)bi * NN + j) * FE);
        dst[0] = src[0];
        dst[1] = src[1];
    }
}

// One-time weight transposes: wXt[h][k] = WX[k][h].
__global__ __launch_bounds__(256) void prep4(
    const float* __restrict__ Wm1, const float* __restrict__ Wm2,
    const float* __restrict__ Wo1, const float* __restrict__ Wo2,
    const float* __restrict__ Wdn, const float* __restrict__ Wde,
    float* __restrict__ wm1t, float* __restrict__ wm2t,
    float* __restrict__ wo1t, float* __restrict__ wo2t,
    float* __restrict__ wdnt, float* __restrict__ wdet) {
    int idx = blockIdx.x * 256 + threadIdx.x;  // 0..32767
    int k = idx >> 7;        // 0..255
    int h = idx & 127;
    wm1t[h * 256 + k] = Wm1[idx];
    wm2t[h * 256 + k] = Wm2[idx];
    wo1t[h * 256 + k] = Wo1[idx];
    if (idx < 16384) {
        int k2 = idx >> 7;   // 0..127
        wo2t[h * 128 + k2] = Wo2[idx];
    }
    if (idx < 8192) {
        int kd = idx >> 6;   // 0..127
        int d = idx & 63;
        wdnt[d * 128 + kd] = Wdn[idx];
        wdet[d * 128 + kd] = Wde[idx];
    }
}

// K1: [node_fts | hidden] @ [W_m1 | W_m2 | W_o1] with transposed-weight float4 reads.
__global__ __launch_bounds__(256) void k1_gemm(
    const float* __restrict__ base_node, const float* __restrict__ hidden,
    const float* __restrict__ hints, const float* __restrict__ Wh,
    const float* __restrict__ wm1t, const float* __restrict__ wm2t,
    const float* __restrict__ wo1t, const float* __restrict__ mg,
    float* __restrict__ m1p, float* __restrict__ m2, float* __restrict__ o1,
    int t) {
    __shared__ float zs[8][256];
    const int lane = threadIdx.x & 127;
    const int half = threadIdx.x >> 7;
    const int row0 = blockIdx.x * 8;

#pragma unroll
    for (int r = 0; r < 4; ++r) {
        int rr = half * 4 + r;
        int row = row0 + rr;
        float nf = base_node[row * HH + lane];
        if (t > 0) {
            const float* hr = hints + ((size_t)(t - 1) * BB * NN + row) * FH;
#pragma unroll
            for (int f = 0; f < FH; ++f) nf += hr[f] * Wh[f * HH + lane];
        }
        zs[rr][lane] = nf;
        zs[rr][128 + lane] = hidden[row * HH + lane];
    }
    __syncthreads();

    float acc[4][3];
#pragma unroll
    for (int r = 0; r < 4; ++r) { acc[r][0] = 0.f; acc[r][1] = 0.f; acc[r][2] = 0.f; }
    const int h4 = half * 4;
    const float4* w1p = (const float4*)(wm1t + lane * 256);
    const float4* w2p = (const float4*)(wm2t + lane * 256);
    const float4* w3p = (const float4*)(wo1t + lane * 256);

#pragma unroll 4
    for (int kk = 0; kk < 64; ++kk) {
        float4 w1 = w1p[kk];
        float4 w2 = w2p[kk];
        float4 w3 = w3p[kk];
        float4 z0 = *(const float4*)&zs[h4 + 0][kk * 4];
        float4 z1 = *(const float4*)&zs[h4 + 1][kk * 4];
        float4 z2 = *(const float4*)&zs[h4 + 2][kk * 4];
        float4 z3 = *(const float4*)&zs[h4 + 3][kk * 4];
#define K1C(ZR, R)                                                   \
        acc[R][0] = fmaf(ZR.x, w1.x, acc[R][0]);                     \
        acc[R][0] = fmaf(ZR.y, w1.y, acc[R][0]);                     \
        acc[R][0] = fmaf(ZR.z, w1.z, acc[R][0]);                     \
        acc[R][0] = fmaf(ZR.w, w1.w, acc[R][0]);                     \
        acc[R][1] = fmaf(ZR.x, w2.x, acc[R][1]);                     \
        acc[R][1] = fmaf(ZR.y, w2.y, acc[R][1]);                     \
        acc[R][1] = fmaf(ZR.z, w2.z, acc[R][1]);                     \
        acc[R][1] = fmaf(ZR.w, w2.w, acc[R][1]);                     \
        acc[R][2] = fmaf(ZR.x, w3.x, acc[R][2]);                     \
        acc[R][2] = fmaf(ZR.y, w3.y, acc[R][2]);                     \
        acc[R][2] = fmaf(ZR.z, w3.z, acc[R][2]);                     \
        acc[R][2] = fmaf(ZR.w, w3.w, acc[R][2]);
        K1C(z0, 0) K1C(z1, 1) K1C(z2, 2) K1C(z3, 3)
#undef K1C
    }

#pragma unroll
    for (int r = 0; r < 4; ++r) {
        int row = row0 + h4 + r;
        int b = row >> 7;
        m1p[row * HH + lane] = acc[r][0] + mg[b * HH + lane];
        m2[row * HH + lane] = acc[r][1];
        o1[row * HH + lane] = acc[r][2];
    }
}

// K2: 512 threads = 128 h x 4 j-groups. Fixed 8-entry unrolled chunks.
__global__ __launch_bounds__(512) void k2_max(
    const float* __restrict__ eg, const int* __restrict__ jl,
    const int* __restrict__ cnt, const float* __restrict__ We,
    const float* __restrict__ m1p, const float* __restrict__ m2,
    const float* __restrict__ o1, const float* __restrict__ wo2t,
    const float* __restrict__ wdnt, const float* __restrict__ wdet,
    float* __restrict__ hidden, float* __restrict__ out, int t, int last) {
    __shared__ float part[4][HH];
    __shared__ float agg_lds[HH];
    __shared__ float hnew[HH];
    __shared__ int jl_lds[NN];
    const int tid = threadIdx.x;
    const int h = tid & 127;
    const int jg = tid >> 7;   // 0..3
    const int bi = blockIdx.x;
    const int b = bi >> 7;

    const int cp = cnt[bi];    // padded count (multiple of 32, or 0)
    if (tid < NN) jl_lds[tid] = jl[bi * NN + tid];

    const float we0 = We[0 * HH + h], we1 = We[1 * HH + h];
    const float we2 = We[2 * HH + h], we3 = We[3 * HH + h];
    const float we4 = We[4 * HH + h], we5 = We[5 * HH + h];
    const float we6 = We[6 * HH + h], we7 = We[7 * HH + h];
    __syncthreads();

    const float* __restrict__ egb = eg + (size_t)bi * NN * FE;
    const float* __restrict__ m2b = m2 + (size_t)b * NN * HH;
    float M = -3e38f;
    const int nch = cp >> 5;
    for (int ch = 0; ch < nch; ++ch) {
        const int k0 = ch * 32 + jg * 8;
        int jj[8];
#pragma unroll
        for (int s = 0; s < 8; ++s) jj[s] = jl_lds[k0 + s];
        float4 e0[8], e1[8];
#pragma unroll
        for (int s = 0; s < 8; ++s) {
            const float4* ep = (const float4*)(egb + (size_t)(k0 + s) * FE);
            e0[s] = ep[0];
            e1[s] = ep[1];
        }
        float mv[8];
#pragma unroll
        for (int s = 0; s < 8; ++s) mv[s] = m2b[jj[s] * HH + h];
#pragma unroll
        for (int s = 0; s < 8; ++s) {
            float e = e0[s].x * we0;
            e = fmaf(e0[s].y, we1, e);
            e = fmaf(e0[s].z, we2, e);
            e = fmaf(e0[s].w, we3, e);
            e = fmaf(e1[s].x, we4, e);
            e = fmaf(e1[s].y, we5, e);
            e = fmaf(e1[s].z, we6, e);
            e = fmaf(e1[s].w, we7, e);
            M = fmaxf(M, e + mv[s]);
        }
    }
    part[jg][h] = M;
    __syncthreads();

    float Mall = fmaxf(fmaxf(part[0][h], part[1][h]),
                       fmaxf(part[2][h], part[3][h]));
    float agg = (cp > 0) ? fmaxf(m1p[bi * HH + h] + Mall, 0.f) : -1e9f;
    if (jg == 0) agg_lds[h] = agg;
    __syncthreads();

    // o2 dot, k split across jg
    float acc = 0.f;
    const float4* w2p = (const float4*)(wo2t + h * HH + jg * 32);
    const float4* a4 = (const float4*)(agg_lds + jg * 32);
#pragma unroll
    for (int kk = 0; kk < 8; ++kk) {
        float4 a = a4[kk];
        float4 w = w2p[kk];
        acc = fmaf(a.x, w.x, acc);
        acc = fmaf(a.y, w.y, acc);
        acc = fmaf(a.z, w.z, acc);
        acc = fmaf(a.w, w.w, acc);
    }
    part[jg][h] = acc;
    __syncthreads();
    if (jg == 0) {
        float hv = o1[bi * HH + h] + part[0][h] + part[1][h] + part[2][h] + part[3][h];
        hv = fmaxf(hv, 0.f);
        hidden[bi * HH + h] = hv;
        hnew[h] = hv;
    }

    if (last) {
        __syncthreads();
        if (h < DEC) {
            float a = 0.f;
            const float4* h4p = (const float4*)(hnew + jg * 32);
            const float4* ag4 = (const float4*)(agg_lds + jg * 32);
            const float4* wn = (const float4*)(wdnt + h * HH + jg * 32);
            const float4* wd = (const float4*)(wdet + h * HH + jg * 32);
#pragma unroll
            for (int kk = 0; kk < 8; ++kk) {
                float4 hv4 = h4p[kk];
                float4 av4 = ag4[kk];
                float4 wnv = wn[kk];
                float4 wdv = wd[kk];
                a = fmaf(hv4.x, wnv.x, a);
                a = fmaf(hv4.y, wnv.y, a);
                a = fmaf(hv4.z, wnv.z, a);
                a = fmaf(hv4.w, wnv.w, a);
                a = fmaf(av4.x, wdv.x, a);
                a = fmaf(av4.y, wdv.y, a);
                a = fmaf(av4.z, wdv.z, a);
                a = fmaf(av4.w, wdv.w, a);
            }
            part[jg][h] = a;
        }
        __syncthreads();
        if (jg == 0 && h < DEC) {
            out[(((size_t)t * BB + b) * NN + (bi & 127)) * DEC + h] =
                part[0][h] + part[1][h] + part[2][h] + part[3][h];
        }
    }
}

extern "C" void kernel_launch(void* const* d_in, const int* in_sizes, int n_in,
                              void* d_out, int out_size, void* d_ws, size_t ws_size,
                              hipStream_t stream) {
    const float* node = (const float*)d_in[0];
    const float* edge = (const float*)d_in[1];
    const float* graph = (const float*)d_in[2];
    const float* hints = (const float*)d_in[3];
    const int* adj = (const int*)d_in[4];
    const float* Wn = (const float*)d_in[5];
    const float* Wh = (const float*)d_in[6];
    const float* Wee = (const float*)d_in[7];
    const float* Wg = (const float*)d_in[8];
    const float* Wm1 = (const float*)d_in[9];
    const float* Wm2 = (const float*)d_in[10];
    const float* Wme = (const float*)d_in[11];
    const float* Wmg = (const float*)d_in[12];
    const float* Wo1 = (const float*)d_in[13];
    const float* Wo2 = (const float*)d_in[14];
    const float* Wdn = (const float*)d_in[15];
    const float* Wde = (const float*)d_in[16];

    float* ws = (float*)d_ws;
    float* base_node = ws;
    float* We = ws + 524288;
    float* mg = ws + 525312;
    float* m1p = ws + 529408;
    float* m2 = ws + 1053696;
    float* o1 = ws + 1577984;
    float* hidden = ws + 2102272;
    float* eg = ws + 2626560;
    int* jl = (int*)(ws + 6820864);
    int* cnt = (int*)(ws + 7345152);
    float* wm1t = ws + 7349248;
    float* wm2t = ws + 7382016;
    float* wo1t = ws + 7414784;
    float* wo2t = ws + 7447552;
    float* wdnt = ws + 7463936;
    float* wdet = ws + 7472128;
    float* out = (float*)d_out;

    prep1<<<BB * NN, HH, 0, stream>>>(node, Wn, base_node, hidden);
    prep2<<<BB + 1, HH, 0, stream>>>(graph, Wg, Wmg, Wee, Wme, mg, We);
    prep3<<<BB * NN, HH, 0, stream>>>(edge, adj, eg, jl, cnt);
    prep4<<<128, 256, 0, stream>>>(Wm1, Wm2, Wo1, Wo2, Wdn, Wde,
                                   wm1t, wm2t, wo1t, wo2t, wdnt, wdet);

    for (int t = 0; t < TT; ++t) {
        for (int ms = 0; ms < 3; ++ms) {
            k1_gemm<<<BB * NN / 8, 256, 0, stream>>>(base_node, hidden, hints, Wh,
                                                     wm1t, wm2t, wo1t, mg,
                                                     m1p, m2, o1, t);
            k2_max<<<BB * NN, 512, 0, stream>>>(eg, jl, cnt, We, m1p, m2, o1,
                                                wo2t, wdnt, wdet, hidden, out, t,
                                                ms == 2 ? 1 : 0);
        }
    }
}

// Round 4
// 4085.548 us; speedup vs baseline: 1.6326x; 1.6326x over previous
//
#include <hip/hip_runtime.h>
#include <hip/hip_bf16.h>
#include <stdint.h>

#define BB 32
#define NN 128
#define TT 16
#define FN 16
#define FE 8
#define FG 8
#define FH 16
#define HH 128
#define DEC 64

// ws layout (floats):
// base_node @0        [524288]
// We        @524288   [1024]
// mg        @525312   [4096]
// m1p       @529408   [524288]
// m2        @1053696  [524288]
// o1        @1577984  [524288]
// hidden    @2102272  [524288]
// eg16      @2626560  [2097152]  (4096*128 rows x 16B bf16x8)
// jl (int)  @4723712  [524288]
// cnt (int) @5248000  [4096]
// wm1t      @5252096  [32768]
// wm2t      @5284864  [32768]
// wo1t      @5317632  [32768]
// end 5350400 floats = 21.4 MB

__global__ __launch_bounds__(HH) void prep1(const float* __restrict__ node,
                                            const float* __restrict__ Wn,
                                            float* __restrict__ base_node,
                                            float* __restrict__ hidden) {
    int row = blockIdx.x;
    int h = threadIdx.x;
    float acc = 0.f;
#pragma unroll
    for (int f = 0; f < FN; ++f)
        acc += node[row * FN + f] * Wn[f * HH + h];
    base_node[row * HH + h] = acc;
    hidden[row * HH + h] = 0.f;
}

__global__ __launch_bounds__(HH) void prep2(const float* __restrict__ graph,
                                            const float* __restrict__ Wg,
                                            const float* __restrict__ Wmg,
                                            const float* __restrict__ Wee,
                                            const float* __restrict__ Wme,
                                            float* __restrict__ mg,
                                            float* __restrict__ We) {
    int h = threadIdx.x;
    if (blockIdx.x < BB) {
        int b = blockIdx.x;
        __shared__ float gf[HH];
        float acc = 0.f;
#pragma unroll
        for (int f = 0; f < FG; ++f) acc += graph[b * FG + f] * Wg[f * HH + h];
        gf[h] = acc;
        __syncthreads();
        float a2 = 0.f;
#pragma unroll 4
        for (int k = 0; k < HH; ++k) a2 += gf[k] * Wmg[k * HH + h];
        mg[b * HH + h] = a2;
    } else {
#pragma unroll
        for (int f = 0; f < FE; ++f) {
            float acc = 0.f;
#pragma unroll 4
            for (int k = 0; k < HH; ++k) acc += Wee[f * HH + k] * Wme[k * HH + h];
            We[f * HH + h] = acc;
        }
    }
}

__device__ __forceinline__ uint32_t bf16rne(float v) {
    uint32_t b = __float_as_uint(v);
    return (b + 0x7fffu + ((b >> 16) & 1u)) >> 16;
}

// Compact valid senders into bf16-packed rows (one uint4 = 8 bf16 coefs per j);
// pad count to multiple of 8 with duplicates of the first valid entry.
__global__ __launch_bounds__(HH) void prep3(const float* __restrict__ edge,
                                            const int* __restrict__ adj,
                                            uint4* __restrict__ eg16,
                                            int* __restrict__ jl,
                                            int* __restrict__ cnt) {
    int bi = blockIdx.x;
    int j = threadIdx.x;
    __shared__ int w0cnt, totc, j0s;
    bool valid = adj[(size_t)bi * NN + j] > 0;
    unsigned long long mask = __ballot(valid);
    int lane = j & 63;
    int wave = j >> 6;
    int prefix = __popcll(mask & ((1ull << lane) - 1ull));
    int wcount = __popcll(mask);
    if (wave == 0 && lane == 0) w0cnt = wcount;
    __syncthreads();
    int base = (wave == 1) ? w0cnt : 0;
    if (wave == 1 && lane == 0) totc = w0cnt + wcount;
    int pos = base + prefix;
    if (valid && pos == 0) j0s = j;
    __syncthreads();
    int c = totc;
    int cpad = (c + 7) & ~7;
    if (j == 0) cnt[bi] = cpad;

    if (valid) {
        jl[bi * NN + pos] = j;
        const float* src = edge + ((size_t)bi * NN + j) * FE;
        uint4 r;
        r.x = bf16rne(src[0]) | (bf16rne(src[1]) << 16);
        r.y = bf16rne(src[2]) | (bf16rne(src[3]) << 16);
        r.z = bf16rne(src[4]) | (bf16rne(src[5]) << 16);
        r.w = bf16rne(src[6]) | (bf16rne(src[7]) << 16);
        eg16[(size_t)bi * NN + pos] = r;
    }
    if (c > 0 && j >= c && j < cpad) {
        int j0 = j0s;
        jl[bi * NN + j] = j0;
        const float* src = edge + ((size_t)bi * NN + j0) * FE;
        uint4 r;
        r.x = bf16rne(src[0]) | (bf16rne(src[1]) << 16);
        r.y = bf16rne(src[2]) | (bf16rne(src[3]) << 16);
        r.z = bf16rne(src[4]) | (bf16rne(src[5]) << 16);
        r.w = bf16rne(src[6]) | (bf16rne(src[7]) << 16);
        eg16[(size_t)bi * NN + j] = r;
    }
}

// One-time weight transposes for k1: wXt[h][k] = WX[k][h].
__global__ __launch_bounds__(256) void prep4(
    const float* __restrict__ Wm1, const float* __restrict__ Wm2,
    const float* __restrict__ Wo1,
    float* __restrict__ wm1t, float* __restrict__ wm2t,
    float* __restrict__ wo1t) {
    int idx = blockIdx.x * 256 + threadIdx.x;  // 0..32767
    int k = idx >> 7;
    int h = idx & 127;
    wm1t[h * 256 + k] = Wm1[idx];
    wm2t[h * 256 + k] = Wm2[idx];
    wo1t[h * 256 + k] = Wo1[idx];
}

// K1: 16-row tiles, 512 threads (lane=h, quarter=4 rows each).
__global__ __launch_bounds__(512) void k1_gemm(
    const float* __restrict__ base_node, const float* __restrict__ hidden,
    const float* __restrict__ hints, const float* __restrict__ Wh,
    const float* __restrict__ wm1t, const float* __restrict__ wm2t,
    const float* __restrict__ wo1t, const float* __restrict__ mg,
    float* __restrict__ m1p, float* __restrict__ m2, float* __restrict__ o1,
    int t) {
    __shared__ float zs[16][256];
    const int lane = threadIdx.x & 127;
    const int q = threadIdx.x >> 7;      // 0..3
    const int row0 = blockIdx.x * 16;

#pragma unroll
    for (int r = 0; r < 4; ++r) {
        int rr = q * 4 + r;
        int row = row0 + rr;
        float nf = base_node[row * HH + lane];
        if (t > 0) {
            const float* hr = hints + ((size_t)(t - 1) * BB * NN + row) * FH;
#pragma unroll
            for (int f = 0; f < FH; ++f) nf += hr[f] * Wh[f * HH + lane];
        }
        zs[rr][lane] = nf;
        zs[rr][128 + lane] = hidden[row * HH + lane];
    }
    __syncthreads();

    float acc[4][3];
#pragma unroll
    for (int r = 0; r < 4; ++r) { acc[r][0] = 0.f; acc[r][1] = 0.f; acc[r][2] = 0.f; }
    const int q4 = q * 4;
    const float4* w1p = (const float4*)(wm1t + lane * 256);
    const float4* w2p = (const float4*)(wm2t + lane * 256);
    const float4* w3p = (const float4*)(wo1t + lane * 256);

#pragma unroll 4
    for (int kk = 0; kk < 64; ++kk) {
        float4 w1 = w1p[kk];
        float4 w2 = w2p[kk];
        float4 w3 = w3p[kk];
        float4 z0 = *(const float4*)&zs[q4 + 0][kk * 4];
        float4 z1 = *(const float4*)&zs[q4 + 1][kk * 4];
        float4 z2 = *(const float4*)&zs[q4 + 2][kk * 4];
        float4 z3 = *(const float4*)&zs[q4 + 3][kk * 4];
#define K1C(ZR, R)                                                   \
        acc[R][0] = fmaf(ZR.x, w1.x, acc[R][0]);                     \
        acc[R][0] = fmaf(ZR.y, w1.y, acc[R][0]);                     \
        acc[R][0] = fmaf(ZR.z, w1.z, acc[R][0]);                     \
        acc[R][0] = fmaf(ZR.w, w1.w, acc[R][0]);                     \
        acc[R][1] = fmaf(ZR.x, w2.x, acc[R][1]);                     \
        acc[R][1] = fmaf(ZR.y, w2.y, acc[R][1]);                     \
        acc[R][1] = fmaf(ZR.z, w2.z, acc[R][1]);                     \
        acc[R][1] = fmaf(ZR.w, w2.w, acc[R][1]);                     \
        acc[R][2] = fmaf(ZR.x, w3.x, acc[R][2]);                     \
        acc[R][2] = fmaf(ZR.y, w3.y, acc[R][2]);                     \
        acc[R][2] = fmaf(ZR.z, w3.z, acc[R][2]);                     \
        acc[R][2] = fmaf(ZR.w, w3.w, acc[R][2]);
        K1C(z0, 0) K1C(z1, 1) K1C(z2, 2) K1C(z3, 3)
#undef K1C
    }

#pragma unroll
    for (int r = 0; r < 4; ++r) {
        int row = row0 + q4 + r;
        int b = row >> 7;
        m1p[row * HH + lane] = acc[r][0] + mg[b * HH + lane];
        m2[row * HH + lane] = acc[r][1];
        o1[row * HH + lane] = acc[r][2];
    }
}

// K2: 128 threads (h), serial compacted j-loop in unroll-8 batches; bf16 eg rows.
__global__ __launch_bounds__(HH) void k2_max(
    const uint4* __restrict__ eg16, const int* __restrict__ jl,
    const int* __restrict__ cnt, const float* __restrict__ We,
    const float* __restrict__ m1p, const float* __restrict__ m2,
    const float* __restrict__ o1, const float* __restrict__ Wo2,
    const float* __restrict__ Wdn, const float* __restrict__ Wde,
    float* __restrict__ hidden, float* __restrict__ out, int t, int last) {
    __shared__ float agg_lds[HH];
    __shared__ float hnew_lds[HH];
    const int h = threadIdx.x;
    const int bi = blockIdx.x;
    const int b = bi >> 7;

    const float we0 = We[0 * HH + h], we1 = We[1 * HH + h];
    const float we2 = We[2 * HH + h], we3 = We[3 * HH + h];
    const float we4 = We[4 * HH + h], we5 = We[5 * HH + h];
    const float we6 = We[6 * HH + h], we7 = We[7 * HH + h];

    const uint4* __restrict__ egp = eg16 + (size_t)bi * NN;
    const int* __restrict__ jlb = jl + bi * NN;
    const float* __restrict__ m2b = m2 + (size_t)b * NN * HH;
    const int cp = cnt[bi];
    const float m1v = m1p[bi * HH + h];
    const float o1v = o1[bi * HH + h];

    float M = -3e38f;
    const int nch = cp >> 3;
    for (int ch = 0; ch < nch; ++ch) {
        const int k0 = ch * 8;
        uint4 raw[8];
        int jj[8];
        float mv[8];
#pragma unroll
        for (int s = 0; s < 8; ++s) raw[s] = egp[k0 + s];
#pragma unroll
        for (int s = 0; s < 8; ++s) jj[s] = jlb[k0 + s];
#pragma unroll
        for (int s = 0; s < 8; ++s) mv[s] = m2b[jj[s] * HH + h];
#pragma unroll
        for (int s = 0; s < 8; ++s) {
            uint32_t x = raw[s].x, y = raw[s].y, z = raw[s].z, w = raw[s].w;
            float e = __uint_as_float(x << 16) * we0;
            e = fmaf(__uint_as_float(x & 0xffff0000u), we1, e);
            e = fmaf(__uint_as_float(y << 16), we2, e);
            e = fmaf(__uint_as_float(y & 0xffff0000u), we3, e);
            e = fmaf(__uint_as_float(z << 16), we4, e);
            e = fmaf(__uint_as_float(z & 0xffff0000u), we5, e);
            e = fmaf(__uint_as_float(w << 16), we6, e);
            e = fmaf(__uint_as_float(w & 0xffff0000u), we7, e);
            M = fmaxf(M, e + mv[s]);
        }
    }
    float agg = (cp > 0) ? fmaxf(m1v + M, 0.f) : -1e9f;
    agg_lds[h] = agg;
    __syncthreads();

    float acc = o1v;
    const float4* a4 = (const float4*)agg_lds;
#pragma unroll 8
    for (int kk = 0; kk < 32; ++kk) {
        float4 a = a4[kk];
        acc = fmaf(a.x, Wo2[(kk * 4 + 0) * HH + h], acc);
        acc = fmaf(a.y, Wo2[(kk * 4 + 1) * HH + h], acc);
        acc = fmaf(a.z, Wo2[(kk * 4 + 2) * HH + h], acc);
        acc = fmaf(a.w, Wo2[(kk * 4 + 3) * HH + h], acc);
    }
    float hv = fmaxf(acc, 0.f);
    hidden[bi * HH + h] = hv;

    if (last) {
        hnew_lds[h] = hv;
        __syncthreads();
        if (h < DEC) {
            float a = 0.f, e2 = 0.f;
            const float4* h4p = (const float4*)hnew_lds;
#pragma unroll 8
            for (int kk = 0; kk < 32; ++kk) {
                float4 hv4 = h4p[kk];
                float4 av4 = a4[kk];
                a = fmaf(hv4.x, Wdn[(kk * 4 + 0) * DEC + h], a);
                a = fmaf(hv4.y, Wdn[(kk * 4 + 1) * DEC + h], a);
                a = fmaf(hv4.z, Wdn[(kk * 4 + 2) * DEC + h], a);
                a = fmaf(hv4.w, Wdn[(kk * 4 + 3) * DEC + h], a);
                e2 = fmaf(av4.x, Wde[(kk * 4 + 0) * DEC + h], e2);
                e2 = fmaf(av4.y, Wde[(kk * 4 + 1) * DEC + h], e2);
                e2 = fmaf(av4.z, Wde[(kk * 4 + 2) * DEC + h], e2);
                e2 = fmaf(av4.w, Wde[(kk * 4 + 3) * DEC + h], e2);
            }
            out[(((size_t)t * BB + b) * NN + (bi & 127)) * DEC + h] = a + e2;
        }
    }
}

extern "C" void kernel_launch(void* const* d_in, const int* in_sizes, int n_in,
                              void* d_out, int out_size, void* d_ws, size_t ws_size,
                              hipStream_t stream) {
    const float* node = (const float*)d_in[0];
    const float* edge = (const float*)d_in[1];
    const float* graph = (const float*)d_in[2];
    const float* hints = (const float*)d_in[3];
    const int* adj = (const int*)d_in[4];
    const float* Wn = (const float*)d_in[5];
    const float* Wh = (const float*)d_in[6];
    const float* Wee = (const float*)d_in[7];
    const float* Wg = (const float*)d_in[8];
    const float* Wm1 = (const float*)d_in[9];
    const float* Wm2 = (const float*)d_in[10];
    const float* Wme = (const float*)d_in[11];
    const float* Wmg = (const float*)d_in[12];
    const float* Wo1 = (const float*)d_in[13];
    const float* Wo2 = (const float*)d_in[14];
    const float* Wdn = (const float*)d_in[15];
    const float* Wde = (const float*)d_in[16];

    float* ws = (float*)d_ws;
    float* base_node = ws;
    float* We = ws + 524288;
    float* mg = ws + 525312;
    float* m1p = ws + 529408;
    float* m2 = ws + 1053696;
    float* o1 = ws + 1577984;
    float* hidden = ws + 2102272;
    uint4* eg16 = (uint4*)(ws + 2626560);
    int* jl = (int*)(ws + 4723712);
    int* cnt = (int*)(ws + 5248000);
    float* wm1t = ws + 5252096;
    float* wm2t = ws + 5284864;
    float* wo1t = ws + 5317632;
    float* out = (float*)d_out;

    prep1<<<BB * NN, HH, 0, stream>>>(node, Wn, base_node, hidden);
    prep2<<<BB + 1, HH, 0, stream>>>(graph, Wg, Wmg, Wee, Wme, mg, We);
    prep3<<<BB * NN, HH, 0, stream>>>(edge, adj, eg16, jl, cnt);
    prep4<<<128, 256, 0, stream>>>(Wm1, Wm2, Wo1, wm1t, wm2t, wo1t);

    for (int t = 0; t < TT; ++t) {
        for (int ms = 0; ms < 3; ++ms) {
            k1_gemm<<<BB * NN / 16, 512, 0, stream>>>(base_node, hidden, hints, Wh,
                                                      wm1t, wm2t, wo1t, mg,
                                                      m1p, m2, o1, t);
            k2_max<<<BB * NN, HH, 0, stream>>>(eg16, jl, cnt, We, m1p, m2, o1,
                                               Wo2, Wdn, Wde, hidden, out, t,
                                               ms == 2 ? 1 : 0);
        }
    }
}

// Round 5
// 2993.666 us; speedup vs baseline: 2.2280x; 1.3647x over previous
//
#include <hip/hip_runtime.h>
#include <hip/hip_bf16.h>
#include <stdint.h>

#define BB 32
#define NN 128
#define TT 16
#define FN 16
#define FE 8
#define FG 8
#define FH 16
#define HH 128
#define DEC 64

// ws layout (floats):
// base_node @0        [524288]
// We        @524288   [1024]
// mg        @525312   [4096]
// m1p       @529408   [524288]
// m2        @1053696  [524288]
// o1        @1577984  [524288]
// hidden    @2102272  [524288]
// eg16      @2626560  [2097152]  (4096*128 rows x 16B bf16x8)
// jl (int)  @4723712  [524288]
// cnt (int) @5248000  [4096]
// end 5252096 floats = 21.0 MB

__global__ __launch_bounds__(HH) void prep1(const float* __restrict__ node,
                                            const float* __restrict__ Wn,
                                            float* __restrict__ base_node,
                                            float* __restrict__ hidden) {
    int row = blockIdx.x;
    int h = threadIdx.x;
    float acc = 0.f;
#pragma unroll
    for (int f = 0; f < FN; ++f)
        acc += node[row * FN + f] * Wn[f * HH + h];
    base_node[row * HH + h] = acc;
    hidden[row * HH + h] = 0.f;
}

__global__ __launch_bounds__(HH) void prep2(const float* __restrict__ graph,
                                            const float* __restrict__ Wg,
                                            const float* __restrict__ Wmg,
                                            const float* __restrict__ Wee,
                                            const float* __restrict__ Wme,
                                            float* __restrict__ mg,
                                            float* __restrict__ We) {
    int h = threadIdx.x;
    if (blockIdx.x < BB) {
        int b = blockIdx.x;
        __shared__ float gf[HH];
        float acc = 0.f;
#pragma unroll
        for (int f = 0; f < FG; ++f) acc += graph[b * FG + f] * Wg[f * HH + h];
        gf[h] = acc;
        __syncthreads();
        float a2 = 0.f;
#pragma unroll 4
        for (int k = 0; k < HH; ++k) a2 += gf[k] * Wmg[k * HH + h];
        mg[b * HH + h] = a2;
    } else {
#pragma unroll
        for (int f = 0; f < FE; ++f) {
            float acc = 0.f;
#pragma unroll 4
            for (int k = 0; k < HH; ++k) acc += Wee[f * HH + k] * Wme[k * HH + h];
            We[f * HH + h] = acc;
        }
    }
}

__device__ __forceinline__ uint32_t bf16rne(float v) {
    uint32_t b = __float_as_uint(v);
    return (b + 0x7fffu + ((b >> 16) & 1u)) >> 16;
}

// Compact valid senders into bf16-packed rows; pad count to multiple of 8
// with duplicates of the first valid entry (max is idempotent).
__global__ __launch_bounds__(HH) void prep3(const float* __restrict__ edge,
                                            const int* __restrict__ adj,
                                            uint4* __restrict__ eg16,
                                            int* __restrict__ jl,
                                            int* __restrict__ cnt) {
    int bi = blockIdx.x;
    int j = threadIdx.x;
    __shared__ int w0cnt, totc, j0s;
    bool valid = adj[(size_t)bi * NN + j] > 0;
    unsigned long long mask = __ballot(valid);
    int lane = j & 63;
    int wave = j >> 6;
    int prefix = __popcll(mask & ((1ull << lane) - 1ull));
    int wcount = __popcll(mask);
    if (wave == 0 && lane == 0) w0cnt = wcount;
    __syncthreads();
    int base = (wave == 1) ? w0cnt : 0;
    if (wave == 1 && lane == 0) totc = w0cnt + wcount;
    int pos = base + prefix;
    if (valid && pos == 0) j0s = j;
    __syncthreads();
    int c = totc;
    int cpad = (c + 7) & ~7;
    if (j == 0) cnt[bi] = cpad;

    if (valid) {
        jl[bi * NN + pos] = j;
        const float* src = edge + ((size_t)bi * NN + j) * FE;
        uint4 r;
        r.x = bf16rne(src[0]) | (bf16rne(src[1]) << 16);
        r.y = bf16rne(src[2]) | (bf16rne(src[3]) << 16);
        r.z = bf16rne(src[4]) | (bf16rne(src[5]) << 16);
        r.w = bf16rne(src[6]) | (bf16rne(src[7]) << 16);
        eg16[(size_t)bi * NN + pos] = r;
    }
    if (c > 0 && j >= c && j < cpad) {
        int j0 = j0s;
        jl[bi * NN + j] = j0;
        const float* src = edge + ((size_t)bi * NN + j0) * FE;
        uint4 r;
        r.x = bf16rne(src[0]) | (bf16rne(src[1]) << 16);
        r.y = bf16rne(src[2]) | (bf16rne(src[3]) << 16);
        r.z = bf16rne(src[4]) | (bf16rne(src[5]) << 16);
        r.w = bf16rne(src[6]) | (bf16rne(src[7]) << 16);
        eg16[(size_t)bi * NN + j] = r;
    }
}

// K1: 256 threads, 16 rows/block, coalesced [k][h] weight reads.
// Each thread: 8 rows x 3 outputs. XCD-swizzled tile id.
__global__ __launch_bounds__(256) void k1_gemm(
    const float* __restrict__ base_node, const float* __restrict__ hidden,
    const float* __restrict__ hints, const float* __restrict__ Wh,
    const float* __restrict__ Wm1, const float* __restrict__ Wm2,
    const float* __restrict__ Wo1, const float* __restrict__ mg,
    float* __restrict__ m1p, float* __restrict__ m2, float* __restrict__ o1,
    int t) {
    __shared__ float zs[16][256];
    const int lane = threadIdx.x & 127;
    const int half = threadIdx.x >> 7;
    // XCD swizzle: 256 blocks, XCD x gets tiles [x*32,(x+1)*32) = batches 4x..4x+3
    const int bid = blockIdx.x;
    const int tile = (bid & 7) * 32 + (bid >> 3);
    const int row0 = tile * 16;

#pragma unroll
    for (int r = 0; r < 8; ++r) {
        int rr = half * 8 + r;
        int row = row0 + rr;
        float nf = base_node[row * HH + lane];
        if (t > 0) {
            const float* hr = hints + ((size_t)(t - 1) * BB * NN + row) * FH;
#pragma unroll
            for (int f = 0; f < FH; ++f) nf += hr[f] * Wh[f * HH + lane];
        }
        zs[rr][lane] = nf;
        zs[rr][128 + lane] = hidden[row * HH + lane];
    }
    __syncthreads();

    float acc[8][3];
#pragma unroll
    for (int r = 0; r < 8; ++r) {
        acc[r][0] = 0.f; acc[r][1] = 0.f; acc[r][2] = 0.f;
    }
    const int h8 = half * 8;

#pragma unroll 2
    for (int kk = 0; kk < 64; ++kk) {
        const int k0 = kk * 4;
        float w1[4], w2[4], w3[4];
#pragma unroll
        for (int u = 0; u < 4; ++u) {
            w1[u] = Wm1[(k0 + u) * HH + lane];   // coalesced 512B/wave
            w2[u] = Wm2[(k0 + u) * HH + lane];
            w3[u] = Wo1[(k0 + u) * HH + lane];
        }
#pragma unroll
        for (int r = 0; r < 8; ++r) {
            float4 zv = *(const float4*)&zs[h8 + r][k0];  // uniform -> LDS broadcast
            acc[r][0] = fmaf(zv.x, w1[0], acc[r][0]);
            acc[r][0] = fmaf(zv.y, w1[1], acc[r][0]);
            acc[r][0] = fmaf(zv.z, w1[2], acc[r][0]);
            acc[r][0] = fmaf(zv.w, w1[3], acc[r][0]);
            acc[r][1] = fmaf(zv.x, w2[0], acc[r][1]);
            acc[r][1] = fmaf(zv.y, w2[1], acc[r][1]);
            acc[r][1] = fmaf(zv.z, w2[2], acc[r][1]);
            acc[r][1] = fmaf(zv.w, w2[3], acc[r][1]);
            acc[r][2] = fmaf(zv.x, w3[0], acc[r][2]);
            acc[r][2] = fmaf(zv.y, w3[1], acc[r][2]);
            acc[r][2] = fmaf(zv.z, w3[2], acc[r][2]);
            acc[r][2] = fmaf(zv.w, w3[3], acc[r][2]);
        }
    }

#pragma unroll
    for (int r = 0; r < 8; ++r) {
        int row = row0 + h8 + r;
        int b = row >> 7;
        m1p[row * HH + lane] = acc[r][0] + mg[b * HH + lane];
        m2[row * HH + lane] = acc[r][1];
        o1[row * HH + lane] = acc[r][2];
    }
}

// K2: 128 threads (h), serial compacted j-loop, unroll-8 batches, bf16 eg rows.
// XCD-swizzled so blocks of the same batch share an XCD-L2 with k1's writes.
__global__ __launch_bounds__(HH) void k2_max(
    const uint4* __restrict__ eg16, const int* __restrict__ jl,
    const int* __restrict__ cnt, const float* __restrict__ We,
    const float* __restrict__ m1p, const float* __restrict__ m2,
    const float* __restrict__ o1, const float* __restrict__ Wo2,
    const float* __restrict__ Wdn, const float* __restrict__ Wde,
    float* __restrict__ hidden, float* __restrict__ out, int t, int last) {
    __shared__ float agg_lds[HH];
    __shared__ float hnew_lds[HH];
    const int h = threadIdx.x;
    // XCD swizzle: 4096 blocks; XCD x gets bi [x*512,(x+1)*512) = batches 4x..4x+3
    const int bid = blockIdx.x;
    const int bi = (bid & 7) * 512 + (bid >> 3);
    const int b = bi >> 7;

    const float we0 = We[0 * HH + h], we1 = We[1 * HH + h];
    const float we2 = We[2 * HH + h], we3 = We[3 * HH + h];
    const float we4 = We[4 * HH + h], we5 = We[5 * HH + h];
    const float we6 = We[6 * HH + h], we7 = We[7 * HH + h];

    const uint4* __restrict__ egp = eg16 + (size_t)bi * NN;
    const int* __restrict__ jlb = jl + bi * NN;
    const float* __restrict__ m2b = m2 + (size_t)b * NN * HH;
    const int cp = cnt[bi];
    const float m1v = m1p[bi * HH + h];
    const float o1v = o1[bi * HH + h];

    float M = -3e38f;
    const int nch = cp >> 3;
    for (int ch = 0; ch < nch; ++ch) {
        const int k0 = ch * 8;
        uint4 raw[8];
        int jj[8];
        float mv[8];
#pragma unroll
        for (int s = 0; s < 8; ++s) raw[s] = egp[k0 + s];
#pragma unroll
        for (int s = 0; s < 8; ++s) jj[s] = jlb[k0 + s];
#pragma unroll
        for (int s = 0; s < 8; ++s) mv[s] = m2b[jj[s] * HH + h];
#pragma unroll
        for (int s = 0; s < 8; ++s) {
            uint32_t x = raw[s].x, y = raw[s].y, z = raw[s].z, w = raw[s].w;
            float e = __uint_as_float(x << 16) * we0;
            e = fmaf(__uint_as_float(x & 0xffff0000u), we1, e);
            e = fmaf(__uint_as_float(y << 16), we2, e);
            e = fmaf(__uint_as_float(y & 0xffff0000u), we3, e);
            e = fmaf(__uint_as_float(z << 16), we4, e);
            e = fmaf(__uint_as_float(z & 0xffff0000u), we5, e);
            e = fmaf(__uint_as_float(w << 16), we6, e);
            e = fmaf(__uint_as_float(w & 0xffff0000u), we7, e);
            M = fmaxf(M, e + mv[s]);
        }
    }
    float agg = (cp > 0) ? fmaxf(m1v + M, 0.f) : -1e9f;
    agg_lds[h] = agg;
    __syncthreads();

    float acc = o1v;
    const float4* a4 = (const float4*)agg_lds;
#pragma unroll 8
    for (int kk = 0; kk < 32; ++kk) {
        float4 a = a4[kk];
        acc = fmaf(a.x, Wo2[(kk * 4 + 0) * HH + h], acc);
        acc = fmaf(a.y, Wo2[(kk * 4 + 1) * HH + h], acc);
        acc = fmaf(a.z, Wo2[(kk * 4 + 2) * HH + h], acc);
        acc = fmaf(a.w, Wo2[(kk * 4 + 3) * HH + h], acc);
    }
    float hv = fmaxf(acc, 0.f);
    hidden[bi * HH + h] = hv;

    if (last) {
        hnew_lds[h] = hv;
        __syncthreads();
        if (h < DEC) {
            float a = 0.f, e2 = 0.f;
            const float4* h4p = (const float4*)hnew_lds;
#pragma unroll 8
            for (int kk = 0; kk < 32; ++kk) {
                float4 hv4 = h4p[kk];
                float4 av4 = a4[kk];
                a = fmaf(hv4.x, Wdn[(kk * 4 + 0) * DEC + h], a);
                a = fmaf(hv4.y, Wdn[(kk * 4 + 1) * DEC + h], a);
                a = fmaf(hv4.z, Wdn[(kk * 4 + 2) * DEC + h], a);
                a = fmaf(hv4.w, Wdn[(kk * 4 + 3) * DEC + h], a);
                e2 = fmaf(av4.x, Wde[(kk * 4 + 0) * DEC + h], e2);
                e2 = fmaf(av4.y, Wde[(kk * 4 + 1) * DEC + h], e2);
                e2 = fmaf(av4.z, Wde[(kk * 4 + 2) * DEC + h], e2);
                e2 = fmaf(av4.w, Wde[(kk * 4 + 3) * DEC + h], e2);
            }
            out[(((size_t)t * BB + b) * NN + (bi & 127)) * DEC + h] = a + e2;
        }
    }
}

extern "C" void kernel_launch(void* const* d_in, const int* in_sizes, int n_in,
                              void* d_out, int out_size, void* d_ws, size_t ws_size,
                              hipStream_t stream) {
    const float* node = (const float*)d_in[0];
    const float* edge = (const float*)d_in[1];
    const float* graph = (const float*)d_in[2];
    const float* hints = (const float*)d_in[3];
    const int* adj = (const int*)d_in[4];
    const float* Wn = (const float*)d_in[5];
    const float* Wh = (const float*)d_in[6];
    const float* Wee = (const float*)d_in[7];
    const float* Wg = (const float*)d_in[8];
    const float* Wm1 = (const float*)d_in[9];
    const float* Wm2 = (const float*)d_in[10];
    const float* Wme = (const float*)d_in[11];
    const float* Wmg = (const float*)d_in[12];
    const float* Wo1 = (const float*)d_in[13];
    const float* Wo2 = (const float*)d_in[14];
    const float* Wdn = (const float*)d_in[15];
    const float* Wde = (const float*)d_in[16];

    float* ws = (float*)d_ws;
    float* base_node = ws;
    float* We = ws + 524288;
    float* mg = ws + 525312;
    float* m1p = ws + 529408;
    float* m2 = ws + 1053696;
    float* o1 = ws + 1577984;
    float* hidden = ws + 2102272;
    uint4* eg16 = (uint4*)(ws + 2626560);
    int* jl = (int*)(ws + 4723712);
    int* cnt = (int*)(ws + 5248000);
    float* out = (float*)d_out;

    prep1<<<BB * NN, HH, 0, stream>>>(node, Wn, base_node, hidden);
    prep2<<<BB + 1, HH, 0, stream>>>(graph, Wg, Wmg, Wee, Wme, mg, We);
    prep3<<<BB * NN, HH, 0, stream>>>(edge, adj, eg16, jl, cnt);

    for (int t = 0; t < TT; ++t) {
        for (int ms = 0; ms < 3; ++ms) {
            k1_gemm<<<BB * NN / 16, 256, 0, stream>>>(base_node, hidden, hints, Wh,
                                                      Wm1, Wm2, Wo1, mg,
                                                      m1p, m2, o1, t);
            k2_max<<<BB * NN, HH, 0, stream>>>(eg16, jl, cnt, We, m1p, m2, o1,
                                               Wo2, Wdn, Wde, hidden, out, t,
                                               ms == 2 ? 1 : 0);
        }
    }
}

// Round 6
// 2530.291 us; speedup vs baseline: 2.6360x; 1.1831x over previous
//
#include <hip/hip_runtime.h>
#include <hip/hip_bf16.h>
#include <stdint.h>

#define BB 32
#define NN 128
#define TT 16
#define FN 16
#define FE 8
#define FG 8
#define FH 16
#define HH 128
#define DEC 64

// ws layout (floats):
// base_node @0        [524288]
// We        @524288   [1024]
// mg        @525312   [4096]
// m1p       @529408   [524288]
// m2        @1053696  [524288]
// o1        @1577984  [524288]
// hidden    @2102272  [524288]
// eg16      @2626560  [2097152]  (4096*128 rows x 16B bf16x8)
// jl (int)  @4723712  [524288]
// cnt (int) @5248000  [4096]
// end 5252096 floats = 21.0 MB

__global__ __launch_bounds__(HH) void prep1(const float* __restrict__ node,
                                            const float* __restrict__ Wn,
                                            float* __restrict__ base_node,
                                            float* __restrict__ hidden) {
    int row = blockIdx.x;
    int h = threadIdx.x;
    float acc = 0.f;
#pragma unroll
    for (int f = 0; f < FN; ++f)
        acc += node[row * FN + f] * Wn[f * HH + h];
    base_node[row * HH + h] = acc;
    hidden[row * HH + h] = 0.f;
}

__global__ __launch_bounds__(HH) void prep2(const float* __restrict__ graph,
                                            const float* __restrict__ Wg,
                                            const float* __restrict__ Wmg,
                                            const float* __restrict__ Wee,
                                            const float* __restrict__ Wme,
                                            float* __restrict__ mg,
                                            float* __restrict__ We) {
    int h = threadIdx.x;
    if (blockIdx.x < BB) {
        int b = blockIdx.x;
        __shared__ float gf[HH];
        float acc = 0.f;
#pragma unroll
        for (int f = 0; f < FG; ++f) acc += graph[b * FG + f] * Wg[f * HH + h];
        gf[h] = acc;
        __syncthreads();
        float a2 = 0.f;
#pragma unroll 4
        for (int k = 0; k < HH; ++k) a2 += gf[k] * Wmg[k * HH + h];
        mg[b * HH + h] = a2;
    } else {
#pragma unroll
        for (int f = 0; f < FE; ++f) {
            float acc = 0.f;
#pragma unroll 4
            for (int k = 0; k < HH; ++k) acc += Wee[f * HH + k] * Wme[k * HH + h];
            We[f * HH + h] = acc;
        }
    }
}

__device__ __forceinline__ uint32_t bf16rne(float v) {
    uint32_t b = __float_as_uint(v);
    return (b + 0x7fffu + ((b >> 16) & 1u)) >> 16;
}

// Compact valid senders into bf16-packed rows; pad count to multiple of 8
// with duplicates of the first valid entry (max is idempotent).
__global__ __launch_bounds__(HH) void prep3(const float* __restrict__ edge,
                                            const int* __restrict__ adj,
                                            uint4* __restrict__ eg16,
                                            int* __restrict__ jl,
                                            int* __restrict__ cnt) {
    int bi = blockIdx.x;
    int j = threadIdx.x;
    __shared__ int w0cnt, totc, j0s;
    bool valid = adj[(size_t)bi * NN + j] > 0;
    unsigned long long mask = __ballot(valid);
    int lane = j & 63;
    int wave = j >> 6;
    int prefix = __popcll(mask & ((1ull << lane) - 1ull));
    int wcount = __popcll(mask);
    if (wave == 0 && lane == 0) w0cnt = wcount;
    __syncthreads();
    int base = (wave == 1) ? w0cnt : 0;
    if (wave == 1 && lane == 0) totc = w0cnt + wcount;
    int pos = base + prefix;
    if (valid && pos == 0) j0s = j;
    __syncthreads();
    int c = totc;
    int cpad = (c + 7) & ~7;
    if (j == 0) cnt[bi] = cpad;

    if (valid) {
        jl[bi * NN + pos] = j;
        const float* src = edge + ((size_t)bi * NN + j) * FE;
        uint4 r;
        r.x = bf16rne(src[0]) | (bf16rne(src[1]) << 16);
        r.y = bf16rne(src[2]) | (bf16rne(src[3]) << 16);
        r.z = bf16rne(src[4]) | (bf16rne(src[5]) << 16);
        r.w = bf16rne(src[6]) | (bf16rne(src[7]) << 16);
        eg16[(size_t)bi * NN + pos] = r;
    }
    if (c > 0 && j >= c && j < cpad) {
        int j0 = j0s;
        jl[bi * NN + j] = j0;
        const float* src = edge + ((size_t)bi * NN + j0) * FE;
        uint4 r;
        r.x = bf16rne(src[0]) | (bf16rne(src[1]) << 16);
        r.y = bf16rne(src[2]) | (bf16rne(src[3]) << 16);
        r.z = bf16rne(src[4]) | (bf16rne(src[5]) << 16);
        r.w = bf16rne(src[6]) | (bf16rne(src[7]) << 16);
        eg16[(size_t)bi * NN + j] = r;
    }
}

// K1: 768 blocks = 256 row-tiles x 3 matrices. Each block: 16 rows x 128 cols
// of one of {m1p, m2, o1}. 256 threads; thread = (half: rows 0-7/8-15, lane=col).
// Coalesced [k][h] weight reads with 8-k register prefetch.
__global__ __launch_bounds__(256) void k1_gemm(
    const float* __restrict__ base_node, const float* __restrict__ hidden,
    const float* __restrict__ hints, const float* __restrict__ Wh,
    const float* __restrict__ Wm1, const float* __restrict__ Wm2,
    const float* __restrict__ Wo1, const float* __restrict__ mg,
    float* __restrict__ m1p, float* __restrict__ m2, float* __restrict__ o1,
    int t) {
    __shared__ float zs[16][256];
    const int lane = threadIdx.x & 127;
    const int half = threadIdx.x >> 7;
    // XCD swizzle: xcd = bid&7 owns tiles 32x..32x+31 (batches 4x..4x+3), 3 mats.
    const int bid = blockIdx.x;
    const int xcd = bid & 7;
    const int idx = bid >> 3;            // 0..95
    const int tile = xcd * 32 + (idx & 31);
    const int mat = idx >> 5;            // 0,1,2
    const int row0 = tile * 16;

#pragma unroll
    for (int r = 0; r < 8; ++r) {
        int rr = half * 8 + r;
        int row = row0 + rr;
        float nf = base_node[row * HH + lane];
        if (t > 0) {
            const float* hr = hints + ((size_t)(t - 1) * BB * NN + row) * FH;
#pragma unroll
            for (int f = 0; f < FH; ++f) nf += hr[f] * Wh[f * HH + lane];
        }
        zs[rr][lane] = nf;
        zs[rr][128 + lane] = hidden[row * HH + lane];
    }
    __syncthreads();

    const float* __restrict__ W = (mat == 0) ? Wm1 : (mat == 1) ? Wm2 : Wo1;

    float acc[8];
#pragma unroll
    for (int r = 0; r < 8; ++r) acc[r] = 0.f;
    const int h8 = half * 8;

    float wc[8];
#pragma unroll
    for (int u = 0; u < 8; ++u) wc[u] = W[u * HH + lane];

    for (int kk = 0; kk < 32; ++kk) {
        const int k0 = kk * 8;
        const int kn = (kk == 31) ? 0 : k0 + 8;   // harmless dummy reload on last
        float wn[8];
#pragma unroll
        for (int u = 0; u < 8; ++u) wn[u] = W[(kn + u) * HH + lane];
#pragma unroll
        for (int r = 0; r < 8; ++r) {
            float4 z0 = *(const float4*)&zs[h8 + r][k0];
            float4 z1 = *(const float4*)&zs[h8 + r][k0 + 4];
            acc[r] = fmaf(z0.x, wc[0], acc[r]);
            acc[r] = fmaf(z0.y, wc[1], acc[r]);
            acc[r] = fmaf(z0.z, wc[2], acc[r]);
            acc[r] = fmaf(z0.w, wc[3], acc[r]);
            acc[r] = fmaf(z1.x, wc[4], acc[r]);
            acc[r] = fmaf(z1.y, wc[5], acc[r]);
            acc[r] = fmaf(z1.z, wc[6], acc[r]);
            acc[r] = fmaf(z1.w, wc[7], acc[r]);
        }
#pragma unroll
        for (int u = 0; u < 8; ++u) wc[u] = wn[u];
    }

    if (mat == 0) {
#pragma unroll
        for (int r = 0; r < 8; ++r) {
            int row = row0 + h8 + r;
            m1p[row * HH + lane] = acc[r] + mg[(row >> 7) * HH + lane];
        }
    } else {
        float* __restrict__ outp = (mat == 1) ? m2 : o1;
#pragma unroll
        for (int r = 0; r < 8; ++r) {
            int row = row0 + h8 + r;
            outp[row * HH + lane] = acc[r];
        }
    }
}

// K2: 128 threads (h), serial compacted j-loop, unroll-8 batches, bf16 eg rows.
// XCD-swizzled so blocks of the same batch share an XCD-L2 with k1's writes.
__global__ __launch_bounds__(HH) void k2_max(
    const uint4* __restrict__ eg16, const int* __restrict__ jl,
    const int* __restrict__ cnt, const float* __restrict__ We,
    const float* __restrict__ m1p, const float* __restrict__ m2,
    const float* __restrict__ o1, const float* __restrict__ Wo2,
    const float* __restrict__ Wdn, const float* __restrict__ Wde,
    float* __restrict__ hidden, float* __restrict__ out, int t, int last) {
    __shared__ float agg_lds[HH];
    __shared__ float hnew_lds[HH];
    const int h = threadIdx.x;
    const int bid = blockIdx.x;
    const int bi = (bid & 7) * 512 + (bid >> 3);
    const int b = bi >> 7;

    const float we0 = We[0 * HH + h], we1 = We[1 * HH + h];
    const float we2 = We[2 * HH + h], we3 = We[3 * HH + h];
    const float we4 = We[4 * HH + h], we5 = We[5 * HH + h];
    const float we6 = We[6 * HH + h], we7 = We[7 * HH + h];

    const uint4* __restrict__ egp = eg16 + (size_t)bi * NN;
    const int* __restrict__ jlb = jl + bi * NN;
    const float* __restrict__ m2b = m2 + (size_t)b * NN * HH;
    const int cp = cnt[bi];
    const float m1v = m1p[bi * HH + h];
    const float o1v = o1[bi * HH + h];

    float M = -3e38f;
    const int nch = cp >> 3;
    for (int ch = 0; ch < nch; ++ch) {
        const int k0 = ch * 8;
        uint4 raw[8];
        int jj[8];
        float mv[8];
#pragma unroll
        for (int s = 0; s < 8; ++s) raw[s] = egp[k0 + s];
#pragma unroll
        for (int s = 0; s < 8; ++s) jj[s] = jlb[k0 + s];
#pragma unroll
        for (int s = 0; s < 8; ++s) mv[s] = m2b[jj[s] * HH + h];
#pragma unroll
        for (int s = 0; s < 8; ++s) {
            uint32_t x = raw[s].x, y = raw[s].y, z = raw[s].z, w = raw[s].w;
            float e = __uint_as_float(x << 16) * we0;
            e = fmaf(__uint_as_float(x & 0xffff0000u), we1, e);
            e = fmaf(__uint_as_float(y << 16), we2, e);
            e = fmaf(__uint_as_float(y & 0xffff0000u), we3, e);
            e = fmaf(__uint_as_float(z << 16), we4, e);
            e = fmaf(__uint_as_float(z & 0xffff0000u), we5, e);
            e = fmaf(__uint_as_float(w << 16), we6, e);
            e = fmaf(__uint_as_float(w & 0xffff0000u), we7, e);
            M = fmaxf(M, e + mv[s]);
        }
    }
    float agg = (cp > 0) ? fmaxf(m1v + M, 0.f) : -1e9f;
    agg_lds[h] = agg;
    __syncthreads();

    float acc = o1v;
    const float4* a4 = (const float4*)agg_lds;
#pragma unroll 8
    for (int kk = 0; kk < 32; ++kk) {
        float4 a = a4[kk];
        acc = fmaf(a.x, Wo2[(kk * 4 + 0) * HH + h], acc);
        acc = fmaf(a.y, Wo2[(kk * 4 + 1) * HH + h], acc);
        acc = fmaf(a.z, Wo2[(kk * 4 + 2) * HH + h], acc);
        acc = fmaf(a.w, Wo2[(kk * 4 + 3) * HH + h], acc);
    }
    float hv = fmaxf(acc, 0.f);
    hidden[bi * HH + h] = hv;

    if (last) {
        hnew_lds[h] = hv;
        __syncthreads();
        if (h < DEC) {
            float a = 0.f, e2 = 0.f;
            const float4* h4p = (const float4*)hnew_lds;
#pragma unroll 8
            for (int kk = 0; kk < 32; ++kk) {
                float4 hv4 = h4p[kk];
                float4 av4 = a4[kk];
                a = fmaf(hv4.x, Wdn[(kk * 4 + 0) * DEC + h], a);
                a = fmaf(hv4.y, Wdn[(kk * 4 + 1) * DEC + h], a);
                a = fmaf(hv4.z, Wdn[(kk * 4 + 2) * DEC + h], a);
                a = fmaf(hv4.w, Wdn[(kk * 4 + 3) * DEC + h], a);
                e2 = fmaf(av4.x, Wde[(kk * 4 + 0) * DEC + h], e2);
                e2 = fmaf(av4.y, Wde[(kk * 4 + 1) * DEC + h], e2);
                e2 = fmaf(av4.z, Wde[(kk * 4 + 2) * DEC + h], e2);
                e2 = fmaf(av4.w, Wde[(kk * 4 + 3) * DEC + h], e2);
            }
            out[(((size_t)t * BB + b) * NN + (bi & 127)) * DEC + h] = a + e2;
        }
    }
}

extern "C" void kernel_launch(void* const* d_in, const int* in_sizes, int n_in,
                              void* d_out, int out_size, void* d_ws, size_t ws_size,
                              hipStream_t stream) {
    const float* node = (const float*)d_in[0];
    const float* edge = (const float*)d_in[1];
    const float* graph = (const float*)d_in[2];
    const float* hints = (const float*)d_in[3];
    const int* adj = (const int*)d_in[4];
    const float* Wn = (const float*)d_in[5];
    const float* Wh = (const float*)d_in[6];
    const float* Wee = (const float*)d_in[7];
    const float* Wg = (const float*)d_in[8];
    const float* Wm1 = (const float*)d_in[9];
    const float* Wm2 = (const float*)d_in[10];
    const float* Wme = (const float*)d_in[11];
    const float* Wmg = (const float*)d_in[12];
    const float* Wo1 = (const float*)d_in[13];
    const float* Wo2 = (const float*)d_in[14];
    const float* Wdn = (const float*)d_in[15];
    const float* Wde = (const float*)d_in[16];

    float* ws = (float*)d_ws;
    float* base_node = ws;
    float* We = ws + 524288;
    float* mg = ws + 525312;
    float* m1p = ws + 529408;
    float* m2 = ws + 1053696;
    float* o1 = ws + 1577984;
    float* hidden = ws + 2102272;
    uint4* eg16 = (uint4*)(ws + 2626560);
    int* jl = (int*)(ws + 4723712);
    int* cnt = (int*)(ws + 5248000);
    float* out = (float*)d_out;

    prep1<<<BB * NN, HH, 0, stream>>>(node, Wn, base_node, hidden);
    prep2<<<BB + 1, HH, 0, stream>>>(graph, Wg, Wmg, Wee, Wme, mg, We);
    prep3<<<BB * NN, HH, 0, stream>>>(edge, adj, eg16, jl, cnt);

    for (int t = 0; t < TT; ++t) {
        for (int ms = 0; ms < 3; ++ms) {
            k1_gemm<<<768, 256, 0, stream>>>(base_node, hidden, hints, Wh,
                                             Wm1, Wm2, Wo1, mg,
                                             m1p, m2, o1, t);
            k2_max<<<BB * NN, HH, 0, stream>>>(eg16, jl, cnt, We, m1p, m2, o1,
                                               Wo2, Wdn, Wde, hidden, out, t,
                                               ms == 2 ? 1 : 0);
        }
    }
}